// Round 13
// baseline (207.636 us; speedup 1.0000x reference)
//
#include <hip/hip_runtime.h>
#include <hip/hip_bf16.h>

typedef __bf16 bf16x8 __attribute__((ext_vector_type(8)));
typedef float f32x4 __attribute__((ext_vector_type(4)));

#define DMODEL 2048
#define NH 16
#define HD 128
#define PLEN 512
#define QLEN 2048
#define KVLEN 2560

__device__ __forceinline__ void gload_lds16(const void* g, void* l) {
  __builtin_amdgcn_global_load_lds((const __attribute__((address_space(1))) void*)g,
                                   (__attribute__((address_space(3))) void*)l, 16, 0, 0);
}

__device__ __forceinline__ unsigned cvt_pk_bf16(float lo, float hi) {
  unsigned r;
  asm volatile("v_cvt_pk_bf16_f32 %0, %1, %2" : "=v"(r) : "v"(lo), "v"(hi));
  return r;
}

// ---------------- fused prep kernel (r9/r11 proven, unchanged) ----------------
// grid (32,32,7): z<4 -> transpose weight z to bf16; z=4 -> x convert;
// z=5 -> prefix K copy (coalesced); z=6 -> prefix V transpose via LDS (coalesced).
__global__ __launch_bounds__(256) void k_prep(const float* __restrict__ Wq,
                                              const float* __restrict__ Wk,
                                              const float* __restrict__ Wv,
                                              const float* __restrict__ Wo,
                                              const float* __restrict__ x,
                                              const float* __restrict__ pk,
                                              const float* __restrict__ pv,
                                              __bf16* __restrict__ WqT,
                                              __bf16* __restrict__ WkT,
                                              __bf16* __restrict__ WvT,
                                              __bf16* __restrict__ WoT,
                                              __bf16* __restrict__ xb,
                                              __bf16* __restrict__ Kall,
                                              __bf16* __restrict__ VT) {
  __shared__ float tile[64][65];          // z<4 transpose staging
  __shared__ __bf16 Vt[128][66];          // z=6: [hd][64 p + 2 pad]
  const int z = blockIdx.z;
  const int t = threadIdx.x;
  const int tx = t & 63, ty = t >> 6;
  if (z < 4) {
    const float* in = (z == 0) ? Wq : (z == 1) ? Wk : (z == 2) ? Wv : Wo;
    __bf16* out = (z == 0) ? WqT : (z == 1) ? WkT : (z == 2) ? WvT : WoT;
    const int r0 = blockIdx.y * 64, c0 = blockIdx.x * 64;
#pragma unroll
    for (int i = 0; i < 16; ++i) {
      int r = ty + i * 4;
      tile[r][tx] = in[(size_t)(r0 + r) * DMODEL + c0 + tx];
    }
    __syncthreads();
#pragma unroll
    for (int i = 0; i < 16; ++i) {
      int r = ty + i * 4;
      out[(size_t)(c0 + r) * DMODEL + r0 + tx] = (__bf16)tile[tx][r];
    }
  } else if (z == 4) {
    const int r0 = blockIdx.y * 64, c0 = blockIdx.x * 64;
#pragma unroll
    for (int i = 0; i < 16; ++i) {
      int r = ty + i * 4;
      xb[(size_t)(r0 + r) * DMODEL + c0 + tx] = (__bf16)x[(size_t)(r0 + r) * DMODEL + c0 + tx];
    }
  } else if (z == 5) {
    const int blk = blockIdx.y * 32 + blockIdx.x;  // 0..1023
#pragma unroll
    for (int i = 0; i < 4; ++i) {
      int idx = blk * 1024 + i * 256 + t;          // 0..1048575
      int hd = idx & 127;
      int hh = (idx >> 7) & 15;
      int p = idx >> 11;
      Kall[(size_t)hh * KVLEN * HD + (size_t)p * HD + hd] = (__bf16)pk[idx];
    }
  } else {
    const int b = blockIdx.y * 32 + blockIdx.x;    // need 128 blocks
    if (b >= 128) return;
    const int h = b >> 3;
    const int p0 = (b & 7) * 64;
#pragma unroll
    for (int i = 0; i < 32; ++i) {
      int idx = i * 256 + t;       // 8192 = 64 p x 128 hd
      int hd = idx & 127;
      int p = idx >> 7;
      Vt[hd][p] = (__bf16)pv[(size_t)(p0 + p) * DMODEL + h * HD + hd];
    }
    __syncthreads();
    const int wv = t >> 6, l = t & 63;
    const int lp = l & 31;
    if (l < 32) {
#pragma unroll
      for (int j = 0; j < 32; ++j) {
        int hd = wv * 32 + j;
        unsigned u = *(const unsigned*)&Vt[hd][2 * lp];
        *(unsigned*)(VT + (size_t)h * HD * KVLEN + (size_t)hd * KVLEN + p0 + 2 * lp) = u;
      }
    }
  }
}

// ---------------- GEMM staging (round-4 proven) ----------------

template <int BN>
__device__ __forceinline__ void stage_tile(const __bf16* __restrict__ A,
                                           const __bf16* __restrict__ BT,
                                           char* AsmB, char* BsmB,
                                           int m0, int n0, int k0, int w, int l) {
#pragma unroll
  for (int i = 0; i < 2; ++i) {  // A: 128x32 bf16 = 8KB
    int base = i * 4096 + w * 1024;
    int o = base + l * 16;
    int row = o >> 6, col = (o & 63) >> 1;
    gload_lds16(A + (size_t)(m0 + row) * DMODEL + k0 + col, AsmB + base);
  }
  if constexpr (BN == 128) {
#pragma unroll
    for (int i = 0; i < 2; ++i) {
      int base = i * 4096 + w * 1024;
      int o = base + l * 16;
      int row = o >> 6, col = (o & 63) >> 1;
      gload_lds16(BT + (size_t)(n0 + row) * DMODEL + k0 + col, BsmB + base);
    }
  } else {  // BN==64: 4KB
    int base = w * 1024;
    int o = base + l * 16;
    int row = o >> 6, col = (o & 63) >> 1;
    gload_lds16(BT + (size_t)(n0 + row) * DMODEL + k0 + col, BsmB + base);
  }
}

// BK=64 mainloop (r12-proven on gemm_out): two 32-K sub-tiles per barrier pair.
// 128 x 64 output tile, 4 waves, wave (w>>1, w&1) owns a 64x32 quadrant.
template <typename EPI>
__device__ __forceinline__ void gemm_128x64_bk64(const __bf16* __restrict__ A,
                                                 const __bf16* __restrict__ BT,
                                                 int m0, int n0, int w, int l,
                                                 EPI&& epilogue) {
  __shared__ __bf16 Asm[2][2][4096];   // [dbuf][sub][128x32]
  __shared__ __bf16 Bsm[2][2][2048];   // [dbuf][sub][64x32]
  const int lr = l & 15, lg = l >> 4;
  f32x4 acc[4][2];
#pragma unroll
  for (int mi = 0; mi < 4; ++mi)
#pragma unroll
    for (int ni = 0; ni < 2; ++ni) acc[mi][ni] = (f32x4){0.f, 0.f, 0.f, 0.f};

  stage_tile<64>(A, BT, (char*)&Asm[0][0][0], (char*)&Bsm[0][0][0], m0, n0, 0, w, l);
  stage_tile<64>(A, BT, (char*)&Asm[0][1][0], (char*)&Bsm[0][1][0], m0, n0, 32, w, l);
  __syncthreads();
  int cur = 0;
  for (int k0 = 0; k0 < DMODEL; k0 += 64) {
    if (k0 + 64 < DMODEL) {
      stage_tile<64>(A, BT, (char*)&Asm[cur ^ 1][0][0], (char*)&Bsm[cur ^ 1][0][0],
                     m0, n0, k0 + 64, w, l);
      stage_tile<64>(A, BT, (char*)&Asm[cur ^ 1][1][0], (char*)&Bsm[cur ^ 1][1][0],
                     m0, n0, k0 + 96, w, l);
    }
#pragma unroll
    for (int sub = 0; sub < 2; ++sub) {
      const __bf16* Ab = &Asm[cur][sub][0];
      const __bf16* Bb = &Bsm[cur][sub][0];
      bf16x8 af[4], bfv[2];
#pragma unroll
      for (int mi = 0; mi < 4; ++mi)
        af[mi] = *(const bf16x8*)(Ab + ((w >> 1) * 64 + mi * 16 + lr) * 32 + lg * 8);
#pragma unroll
      for (int ni = 0; ni < 2; ++ni)
        bfv[ni] = *(const bf16x8*)(Bb + ((w & 1) * 32 + ni * 16 + lr) * 32 + lg * 8);
      __builtin_amdgcn_s_setprio(1);
#pragma unroll
      for (int mi = 0; mi < 4; ++mi)
#pragma unroll
        for (int ni = 0; ni < 2; ++ni)
          acc[mi][ni] = __builtin_amdgcn_mfma_f32_16x16x32_bf16(af[mi], bfv[ni], acc[mi][ni], 0, 0, 0);
      __builtin_amdgcn_s_setprio(0);
    }
    __syncthreads();
    cur ^= 1;
  }
#pragma unroll
  for (int mi = 0; mi < 4; ++mi)
#pragma unroll
    for (int ni = 0; ni < 2; ++ni)
#pragma unroll
      for (int r = 0; r < 4; ++r) {
        int row = m0 + (w >> 1) * 64 + mi * 16 + lg * 4 + r;
        int col = n0 + (w & 1) * 32 + ni * 16 + lr;
        epilogue(row, col, acc[mi][ni][r]);
      }
}

// z=0: Q (scaled) -> Qs[h][q][hd]; z=1: K -> Kall[h][512+q][hd]; z=2: V -> VT[h][hd][512+q]
// Grid (16,32,3): 128x64 tiles, BK=64, 48KB LDS -> 3 blocks/CU preserved, barriers halved.
__global__ __launch_bounds__(256) void gemm_qkv(const __bf16* __restrict__ xb,
                                                const __bf16* __restrict__ WqT,
                                                const __bf16* __restrict__ WkT,
                                                const __bf16* __restrict__ WvT,
                                                const float* __restrict__ bq,
                                                const float* __restrict__ bk,
                                                const float* __restrict__ bv,
                                                __bf16* __restrict__ Qs,
                                                __bf16* __restrict__ Kall,
                                                __bf16* __restrict__ VT) {
  const int t = threadIdx.x, w = t >> 6, l = t & 63;
  const int m0 = blockIdx.x * 128, n0 = blockIdx.y * 64;
  const int z = blockIdx.z;
  const __bf16* BT = (z == 0) ? WqT : ((z == 1) ? WkT : WvT);
  const float* bias = (z == 0) ? bq : ((z == 1) ? bk : bv);
  gemm_128x64_bk64(xb, BT, m0, n0, w, l, [&](int row, int col, float a) {
    float v = a + bias[col];
    int hh = col >> 7, hd = col & 127;
    if (z == 0) {
      Qs[(size_t)hh * QLEN * HD + (size_t)row * HD + hd] = (__bf16)(v * 0.08838834764831845f);
    } else if (z == 1) {
      Kall[(size_t)hh * KVLEN * HD + (size_t)(PLEN + row) * HD + hd] = (__bf16)v;
    } else {
      VT[(size_t)hh * HD * KVLEN + (size_t)hd * KVLEN + (PLEN + row)] = (__bf16)v;
    }
  });
}

// final: out[q][d] = O[q][:] . WoT[d][:] + bout[d]  (f32 out).  128x64 tiles, 512 blocks.
// (r12-proven BK=64 structure, expressed through the shared helper)
__global__ __launch_bounds__(256) void gemm_out(const __bf16* __restrict__ Ob,
                                                const __bf16* __restrict__ WoT,
                                                const float* __restrict__ bout,
                                                float* __restrict__ out) {
  const int t = threadIdx.x, w = t >> 6, l = t & 63;
  const int m0 = blockIdx.x * 128, n0 = blockIdx.y * 64;
  gemm_128x64_bk64(Ob, WoT, m0, n0, w, l, [&](int row, int col, float a) {
    out[(size_t)row * DMODEL + col] = a + bout[col];
  });
}

// ---------------- attention (r8/r11/r12 exact: balanced K-split + swapped-QK in-register P) ----------------
template <int KS>
__global__ __launch_bounds__(256, 4) void k_attn(const __bf16* __restrict__ Qs,
                                                 const __bf16* __restrict__ Kall,
                                                 const __bf16* __restrict__ VT,
                                                 __bf16* __restrict__ P1buf,
                                                 float* __restrict__ S1buf,
                                                 __bf16* __restrict__ P2buf,
                                                 float* __restrict__ S2buf) {
  __shared__ __bf16 Ksm[2][4096];   // [buf][32 kv][128 hd] (xor-swizzled)
  __shared__ __bf16 Vsm[2][4096];   // [buf][128 hd][32 kv] (xor-swizzled)
  const int id = blockIdx.x;
  const int b = id & 255, k = id >> 8;
  const int h = b >> 4, m = b & 15;
  int qt, z;
  if constexpr (KS == 2) {
    z = k >> 1;
    const int j = 2 * m + (k >> 1);
    qt = (k & 1) ? (31 - j) : j;
  } else {
    z = 0;
    qt = (k & 1) ? (31 - 2 * m) : (2 * m);
  }
  const int t = threadIdx.x, w = t >> 6, l = t & 63;
  const int lr = l & 15, lg = l >> 4;
  const int q0 = qt * 64 + w * 16;
  const __bf16* Qh = Qs + (size_t)h * QLEN * HD;
  const char* Khb = (const char*)(Kall + (size_t)h * KVLEN * HD);
  const char* Vhb = (const char*)(VT + (size_t)h * HD * KVLEN);

  bf16x8 qf[4];
#pragma unroll
  for (int c = 0; c < 4; ++c)
    qf[c] = *(const bf16x8*)(Qh + (size_t)(q0 + lr) * HD + c * 32 + lg * 8);

  f32x4 acc[8];
  float ss;

  auto STAGE = [&](int buf, int kb) {
#pragma unroll
    for (int i = 0; i < 2; ++i) {  // K: 8KB, rows contiguous in global
      int o = (i * 256 + w * 64 + l) * 16;
      int po = o ^ (((o >> 8) & 7) << 4);
      gload_lds16(Khb + (size_t)kb * 256 + po, (char*)&Ksm[buf][0] + i * 4096 + w * 1024);
    }
#pragma unroll
    for (int i = 0; i < 2; ++i) {  // V: 8KB, rows strided KVLEN*2 in global VT
      int o = (i * 256 + w * 64 + l) * 16;
      int po = o ^ (((o >> 7) & 7) << 4);
      int row = po >> 6, colb = po & 63;
      gload_lds16(Vhb + (size_t)row * (KVLEN * 2) + (size_t)kb * 2 + colb,
                  (char*)&Vsm[buf][0] + i * 4096 + w * 1024);
    }
  };

  auto COMPUTE = [&](int buf, int mrel, bool domask) {
    const char* Kb = (const char*)&Ksm[buf][0];
    const char* Vb = (const char*)&Vsm[buf][0];
    f32x4 st0 = {0.f, 0.f, 0.f, 0.f}, st1 = {0.f, 0.f, 0.f, 0.f};
    __builtin_amdgcn_s_setprio(1);
#pragma unroll
    for (int c = 0; c < 4; ++c) {
      int o0 = lr * 256 + c * 64 + lg * 16;        o0 ^= ((o0 >> 8) & 7) << 4;
      int o1 = (16 + lr) * 256 + c * 64 + lg * 16; o1 ^= ((o1 >> 8) & 7) << 4;
      bf16x8 kf0 = *(const bf16x8*)(Kb + o0);
      bf16x8 kf1 = *(const bf16x8*)(Kb + o1);
      st0 = __builtin_amdgcn_mfma_f32_16x16x32_bf16(kf0, qf[c], st0, 0, 0, 0);
      st1 = __builtin_amdgcn_mfma_f32_16x16x32_bf16(kf1, qf[c], st1, 0, 0, 0);
    }
    __builtin_amdgcn_s_setprio(0);
    const int qabs = q0 + lr;
    float e0[4], e1[4];
    float ps = 0.f;
#pragma unroll
    for (int r = 0; r < 4; ++r) {
      e0[r] = __expf(st0[r] - 16.0f);
      e1[r] = __expf(st1[r] - 16.0f);
      if (domask) {
        if (mrel + 4 * lg + r > qabs) e0[r] = 0.f;
        if (mrel + 16 + 4 * lg + r > qabs) e1[r] = 0.f;
      }
      ps += e0[r] + e1[r];
    }
    ss += ps;
    unsigned W0 = cvt_pk_bf16(e0[0], e0[1]);
    unsigned W1 = cvt_pk_bf16(e0[2], e0[3]);
    unsigned W2 = cvt_pk_bf16(e1[0], e1[1]);
    unsigned W3 = cvt_pk_bf16(e1[2], e1[3]);
    const int srcA = lr + (((2 * lg) & 3) << 4);
    const int srcB = lr + (((2 * lg + 1) & 3) << 4);
    unsigned A0 = __shfl(W0, srcA), A1 = __shfl(W1, srcA);
    unsigned A2 = __shfl(W0, srcB), A3 = __shfl(W1, srcB);
    unsigned B0 = __shfl(W2, srcA), B1 = __shfl(W3, srcA);
    unsigned B2 = __shfl(W2, srcB), B3 = __shfl(W3, srcB);
    union { unsigned u[4]; bf16x8 v; } pu;
    pu.u[0] = (lg < 2) ? A0 : B0;
    pu.u[1] = (lg < 2) ? A1 : B1;
    pu.u[2] = (lg < 2) ? A2 : B2;
    pu.u[3] = (lg < 2) ? A3 : B3;
    bf16x8 pf = pu.v;
    __builtin_amdgcn_s_setprio(1);
#pragma unroll
    for (int c = 0; c < 8; ++c) {
      int o = (c * 16 + lr) * 64 + lg * 16; o ^= ((o >> 7) & 7) << 4;
      bf16x8 vf = *(const bf16x8*)(Vb + o);
      acc[c] = __builtin_amdgcn_mfma_f32_16x16x32_bf16(pf, vf, acc[c], 0, 0, 0);
    }
    __builtin_amdgcn_s_setprio(0);
  };

  auto STORE_PHASE = [&](__bf16* PBUF, float* SBUF) {
    const size_t rb = (size_t)(z * NH + h) * QLEN;
    float s = ss;
    s += __shfl_xor(s, 16);
    s += __shfl_xor(s, 32);
    if (l < 16) SBUF[rb + q0 + l] = s;
#pragma unroll
    for (int r = 0; r < 4; ++r) {
      const int row = q0 + lg * 4 + r;
#pragma unroll
      for (int c = 0; c < 8; ++c)
        PBUF[(rb + row) * HD + c * 16 + lr] = (__bf16)acc[c][r];
    }
  };

#pragma unroll
  for (int c = 0; c < 8; ++c) acc[c] = (f32x4){0.f, 0.f, 0.f, 0.f};
  ss = 0.f;
  int cur = 0;
  STAGE(0, z * 32);
  __syncthreads();
#pragma unroll 1
  for (int tt = z; tt < 16; tt += KS) {
    if (tt + KS < 16) STAGE(cur ^ 1, (tt + KS) * 32);
    else STAGE(cur ^ 1, PLEN + z * 32);
    COMPUTE(cur, 0, false);
    __syncthreads();
    cur ^= 1;
  }
  STORE_PHASE(P1buf, S1buf);

#pragma unroll
  for (int c = 0; c < 8; ++c) acc[c] = (f32x4){0.f, 0.f, 0.f, 0.f};
  ss = 0.f;
  const int ntb = 2 * qt + 2;
#pragma unroll 1
  for (int tt = z; tt < ntb; tt += KS) {
    if (tt + KS < ntb) STAGE(cur ^ 1, PLEN + (tt + KS) * 32);
    COMPUTE(cur, tt * 32, tt * 32 + 31 > q0);
    __syncthreads();
    cur ^= 1;
  }
  STORE_PHASE(P2buf, S2buf);
}

// combine K-split partials: Ob = g*ΣP1/Σs1 + ΣP2/Σs2  (vectorized x8, r12 exact)
template <int KS>
__global__ __launch_bounds__(256) void k_combine(const __bf16* __restrict__ P1buf,
                                                 const float* __restrict__ S1buf,
                                                 const __bf16* __restrict__ P2buf,
                                                 const float* __restrict__ S2buf,
                                                 const float* __restrict__ gate,
                                                 __bf16* __restrict__ Ob) {
  const int idx = blockIdx.x * 256 + threadIdx.x;  // 8 elems each
  const int dc = (idx & 15) * 8;
  const int q = (idx >> 4) & 2047;
  const int h = idx >> 15;
  const size_t rq = (size_t)h * QLEN + q;
  float a1[8], a2[8];
#pragma unroll
  for (int j = 0; j < 8; ++j) { a1[j] = 0.f; a2[j] = 0.f; }
  float s1 = 0.f, s2 = 0.f;
#pragma unroll
  for (int zz = 0; zz < KS; ++zz) {
    const size_t zb = (size_t)zz * NH * QLEN;
    bf16x8 p1 = *(const bf16x8*)&P1buf[(zb + rq) * HD + dc];
    bf16x8 p2 = *(const bf16x8*)&P2buf[(zb + rq) * HD + dc];
#pragma unroll
    for (int j = 0; j < 8; ++j) {
      a1[j] += (float)p1[j];
      a2[j] += (float)p2[j];
    }
    s1 += S1buf[zb + rq];
    s2 += S2buf[zb + rq];
  }
  const float f1 = gate[h] / s1;
  const float f2 = 1.0f / s2;
  bf16x8 ov;
#pragma unroll
  for (int j = 0; j < 8; ++j) ov[j] = (__bf16)(a1[j] * f1 + a2[j] * f2);
  *(bf16x8*)&Ob[(size_t)q * DMODEL + h * HD + dc] = ov;
}

// ---------------- launch ----------------

extern "C" void kernel_launch(void* const* d_in, const int* in_sizes, int n_in,
                              void* d_out, int out_size, void* d_ws, size_t ws_size,
                              hipStream_t stream) {
  const float* x    = (const float*)d_in[0];
  const float* pk   = (const float*)d_in[1];
  const float* pv   = (const float*)d_in[2];
  const float* Wq   = (const float*)d_in[3];
  const float* bq   = (const float*)d_in[4];
  const float* Wk   = (const float*)d_in[5];
  const float* bk   = (const float*)d_in[6];
  const float* Wv   = (const float*)d_in[7];
  const float* bv   = (const float*)d_in[8];
  const float* gate = (const float*)d_in[9];
  const float* Wout = (const float*)d_in[10];
  const float* bout = (const float*)d_in[11];
  float* out = (float*)d_out;

  char* ws = (char*)d_ws;
  size_t off = 0;
  auto alc = [&](size_t bytes) -> char* {
    char* p = ws + off;
    off += bytes;
    off = (off + 255) & ~(size_t)255;
    return p;
  };
  __bf16* xb   = (__bf16*)alc((size_t)DMODEL * DMODEL * 2);
  __bf16* WqT  = (__bf16*)alc((size_t)DMODEL * DMODEL * 2);
  __bf16* WkT  = (__bf16*)alc((size_t)DMODEL * DMODEL * 2);
  __bf16* WvT  = (__bf16*)alc((size_t)DMODEL * DMODEL * 2);
  __bf16* WoT  = (__bf16*)alc((size_t)DMODEL * DMODEL * 2);
  __bf16* Qs   = (__bf16*)alc((size_t)NH * QLEN * HD * 2);
  __bf16* Kall = (__bf16*)alc((size_t)NH * KVLEN * HD * 2);
  __bf16* VTa  = (__bf16*)alc((size_t)NH * HD * KVLEN * 2);
  __bf16* Ob   = (__bf16*)alc((size_t)QLEN * DMODEL * 2);

  const size_t per_split = (size_t)NH * QLEN * HD * 2 * 2
                         + (size_t)NH * QLEN * 4 * 2 + 1024;
  int KS = (off + 2 * per_split <= ws_size) ? 2 : 1;
  __bf16* P1buf = (__bf16*)alc((size_t)KS * NH * QLEN * HD * 2);
  __bf16* P2buf = (__bf16*)alc((size_t)KS * NH * QLEN * HD * 2);
  float*  S1buf = (float*)alc((size_t)KS * NH * QLEN * 4);
  float*  S2buf = (float*)alc((size_t)KS * NH * QLEN * 4);

  k_prep<<<dim3(32, 32, 7), 256, 0, stream>>>(Wq, Wk, Wv, Wout, x, pk, pv,
                                              WqT, WkT, WvT, WoT, xb, Kall, VTa);

  gemm_qkv<<<dim3(16, 32, 3), 256, 0, stream>>>(xb, WqT, WkT, WvT, bq, bk, bv, Qs, Kall, VTa);

  const int ncomb = (NH * QLEN * HD / 8) / 256;  // 2048 blocks, 8 elems/thread
  if (KS == 2) {
    k_attn<2><<<1024, 256, 0, stream>>>(Qs, Kall, VTa, P1buf, S1buf, P2buf, S2buf);
    k_combine<2><<<ncomb, 256, 0, stream>>>(P1buf, S1buf, P2buf, S2buf, gate, Ob);
  } else {
    k_attn<1><<<512, 256, 0, stream>>>(Qs, Kall, VTa, P1buf, S1buf, P2buf, S2buf);
    k_combine<1><<<ncomb, 256, 0, stream>>>(P1buf, S1buf, P2buf, S2buf, gate, Ob);
  }
  gemm_out<<<dim3(16, 32), 256, 0, stream>>>(Ob, WoT, bout, out);
}

// Round 15
// 183.022 us; speedup vs baseline: 1.1345x; 1.1345x over previous
//
#include <hip/hip_runtime.h>
#include <hip/hip_bf16.h>

typedef __bf16 bf16x8 __attribute__((ext_vector_type(8)));
typedef __bf16 bf16x4v __attribute__((ext_vector_type(4)));
typedef float f32x4 __attribute__((ext_vector_type(4)));

#define DMODEL 2048
#define NH 16
#define HD 128
#define PLEN 512
#define QLEN 2048
#define KVLEN 2560

__device__ __forceinline__ void gload_lds16(const void* g, void* l) {
  __builtin_amdgcn_global_load_lds((const __attribute__((address_space(1))) void*)g,
                                   (__attribute__((address_space(3))) void*)l, 16, 0, 0);
}

__device__ __forceinline__ unsigned cvt_pk_bf16(float lo, float hi) {
  unsigned r;
  asm volatile("v_cvt_pk_bf16_f32 %0, %1, %2" : "=v"(r) : "v"(lo), "v"(hi));
  return r;
}

// ---------------- fused prep kernel ----------------
// grid (32,32,7): z<4 -> transpose weight z to bf16; z=4 -> x convert (float4);
// z=5 -> prefix K copy (ONE float4 per thread, bounds-exact: 1024*256*4 = 1048576);
// z=6 -> prefix V transpose via LDS (coalesced).
__global__ __launch_bounds__(256) void k_prep(const float* __restrict__ Wq,
                                              const float* __restrict__ Wk,
                                              const float* __restrict__ Wv,
                                              const float* __restrict__ Wo,
                                              const float* __restrict__ x,
                                              const float* __restrict__ pk,
                                              const float* __restrict__ pv,
                                              __bf16* __restrict__ WqT,
                                              __bf16* __restrict__ WkT,
                                              __bf16* __restrict__ WvT,
                                              __bf16* __restrict__ WoT,
                                              __bf16* __restrict__ xb,
                                              __bf16* __restrict__ Kall,
                                              __bf16* __restrict__ VT) {
  __shared__ float tile[64][65];          // z<4 transpose staging
  __shared__ __bf16 Vt[128][66];          // z=6: [hd][64 p + 2 pad]
  const int z = blockIdx.z;
  const int t = threadIdx.x;
  const int tx = t & 63, ty = t >> 6;
  if (z < 4) {
    const float* in = (z == 0) ? Wq : (z == 1) ? Wk : (z == 2) ? Wv : Wo;
    __bf16* out = (z == 0) ? WqT : (z == 1) ? WkT : (z == 2) ? WvT : WoT;
    const int r0 = blockIdx.y * 64, c0 = blockIdx.x * 64;
#pragma unroll
    for (int i = 0; i < 16; ++i) {
      int r = ty + i * 4;
      tile[r][tx] = in[(size_t)(r0 + r) * DMODEL + c0 + tx];
    }
    __syncthreads();
#pragma unroll
    for (int i = 0; i < 16; ++i) {
      int r = ty + i * 4;
      out[(size_t)(c0 + r) * DMODEL + r0 + tx] = (__bf16)tile[tx][r];
    }
  } else if (z == 4) {
    // x convert, float4 reads + 8B writes: 64x64 tile, 16 lanes x 4 cols, 16 rows/iter
    const int r0 = blockIdx.y * 64, c0 = blockIdx.x * 64;
    const int cx = (t & 15) * 4, ry = t >> 4;
#pragma unroll
    for (int i = 0; i < 4; ++i) {
      int r = ry + i * 16;
      float4 v = *(const float4*)&x[(size_t)(r0 + r) * DMODEL + c0 + cx];
      bf16x4v o;
      o[0] = (__bf16)v.x; o[1] = (__bf16)v.y; o[2] = (__bf16)v.z; o[3] = (__bf16)v.w;
      *(bf16x4v*)&xb[(size_t)(r0 + r) * DMODEL + c0 + cx] = o;
    }
  } else if (z == 5) {
    // prefix K copy, one float4 per thread: 1024 blocks * 256 threads * 4 = 1048576 exact.
    // 4-elem chunks are hd-aligned (hd = idx & 127, idx % 4 == 0) so never cross a row.
    const int blk = blockIdx.y * 32 + blockIdx.x;  // 0..1023
    const int idx = (blk * 256 + t) * 4;
    float4 v = *(const float4*)&pk[idx];
    int hd = idx & 127, hh = (idx >> 7) & 15, p = idx >> 11;
    bf16x4v o;
    o[0] = (__bf16)v.x; o[1] = (__bf16)v.y; o[2] = (__bf16)v.z; o[3] = (__bf16)v.w;
    *(bf16x4v*)&Kall[(size_t)hh * KVLEN * HD + (size_t)p * HD + hd] = o;
  } else {
    const int b = blockIdx.y * 32 + blockIdx.x;    // need 128 blocks
    if (b >= 128) return;
    const int h = b >> 3;
    const int p0 = (b & 7) * 64;
#pragma unroll
    for (int i = 0; i < 32; ++i) {
      int idx = i * 256 + t;       // 8192 = 64 p x 128 hd
      int hd = idx & 127;
      int p = idx >> 7;
      Vt[hd][p] = (__bf16)pv[(size_t)(p0 + p) * DMODEL + h * HD + hd];
    }
    __syncthreads();
    const int wv = t >> 6, l = t & 63;
    const int lp = l & 31;
    if (l < 32) {
#pragma unroll
      for (int j = 0; j < 32; ++j) {
        int hd = wv * 32 + j;
        unsigned u = *(const unsigned*)&Vt[hd][2 * lp];
        *(unsigned*)(VT + (size_t)h * HD * KVLEN + (size_t)hd * KVLEN + p0 + 2 * lp) = u;
      }
    }
  }
}

// ---------------- GEMM staging + mainloop (round-4 proven) ----------------

template <int BN>
__device__ __forceinline__ void stage_tile(const __bf16* __restrict__ A,
                                           const __bf16* __restrict__ BT,
                                           char* AsmB, char* BsmB,
                                           int m0, int n0, int k0, int w, int l) {
#pragma unroll
  for (int i = 0; i < 2; ++i) {  // A: 128x32 bf16 = 8KB
    int base = i * 4096 + w * 1024;
    int o = base + l * 16;
    int row = o >> 6, col = (o & 63) >> 1;
    gload_lds16(A + (size_t)(m0 + row) * DMODEL + k0 + col, AsmB + base);
  }
  if constexpr (BN == 128) {
#pragma unroll
    for (int i = 0; i < 2; ++i) {
      int base = i * 4096 + w * 1024;
      int o = base + l * 16;
      int row = o >> 6, col = (o & 63) >> 1;
      gload_lds16(BT + (size_t)(n0 + row) * DMODEL + k0 + col, BsmB + base);
    }
  } else {  // BN==64: 4KB
    int base = w * 1024;
    int o = base + l * 16;
    int row = o >> 6, col = (o & 63) >> 1;
    gload_lds16(BT + (size_t)(n0 + row) * DMODEL + k0 + col, BsmB + base);
  }
}

// BK=32, BN=128 mainloop (r8/r11/r12 proven — gemm_qkv's 72 µs config)
template <int BN>
__device__ __forceinline__ void gemm_mainloop_db(const __bf16* __restrict__ A,
                                                 const __bf16* __restrict__ BT,
                                                 __bf16* Asm, __bf16* Bsm,  // [2][...]
                                                 int m0, int n0, int w, int l,
                                                 f32x4 (&acc)[4][BN / 32]) {
  constexpr int NI = BN / 32;
  constexpr int ABUF = 4096;
  constexpr int BBUF = BN * 32;
  const int lr = l & 15, lg = l >> 4;
  int cur = 0;
  stage_tile<BN>(A, BT, (char*)Asm, (char*)Bsm, m0, n0, 0, w, l);
  __syncthreads();
  for (int k0 = 0; k0 < DMODEL; k0 += 32) {
    if (k0 + 32 < DMODEL)
      stage_tile<BN>(A, BT, (char*)(Asm + (cur ^ 1) * ABUF), (char*)(Bsm + (cur ^ 1) * BBUF),
                     m0, n0, k0 + 32, w, l);
    const __bf16* Ab = Asm + cur * ABUF;
    const __bf16* Bb = Bsm + cur * BBUF;
    bf16x8 af[4], bfv[NI];
#pragma unroll
    for (int mi = 0; mi < 4; ++mi)
      af[mi] = *(const bf16x8*)(Ab + ((w >> 1) * 64 + mi * 16 + lr) * 32 + lg * 8);
#pragma unroll
    for (int ni = 0; ni < NI; ++ni)
      bfv[ni] = *(const bf16x8*)(Bb + ((w & 1) * (BN / 2) + ni * 16 + lr) * 32 + lg * 8);
    __builtin_amdgcn_s_setprio(1);
#pragma unroll
    for (int mi = 0; mi < 4; ++mi)
#pragma unroll
      for (int ni = 0; ni < NI; ++ni)
        acc[mi][ni] = __builtin_amdgcn_mfma_f32_16x16x32_bf16(af[mi], bfv[ni], acc[mi][ni], 0, 0, 0);
    __builtin_amdgcn_s_setprio(0);
    __syncthreads();
    cur ^= 1;
  }
}

// z=0: Q (scaled) -> Qs[h][q][hd]; z=1: K -> Kall[h][512+q][hd]; z=2: V -> VT[h][hd][512+q]
// (r8/r11/r12 exact — proven 72 µs)
__global__ __launch_bounds__(256) void gemm_qkv(const __bf16* __restrict__ xb,
                                                const __bf16* __restrict__ WqT,
                                                const __bf16* __restrict__ WkT,
                                                const __bf16* __restrict__ WvT,
                                                const float* __restrict__ bq,
                                                const float* __restrict__ bk,
                                                const float* __restrict__ bv,
                                                __bf16* __restrict__ Qs,
                                                __bf16* __restrict__ Kall,
                                                __bf16* __restrict__ VT) {
  __shared__ __bf16 Asm[2][4096];
  __shared__ __bf16 Bsm[2][4096];
  const int t = threadIdx.x, w = t >> 6, l = t & 63;
  const int m0 = blockIdx.x * 128, n0 = blockIdx.y * 128;
  const int z = blockIdx.z;
  const __bf16* BT = (z == 0) ? WqT : ((z == 1) ? WkT : WvT);
  const float* bias = (z == 0) ? bq : ((z == 1) ? bk : bv);
  f32x4 acc[4][4];
#pragma unroll
  for (int mi = 0; mi < 4; ++mi)
#pragma unroll
    for (int ni = 0; ni < 4; ++ni) acc[mi][ni] = (f32x4){0.f, 0.f, 0.f, 0.f};
  gemm_mainloop_db<128>(xb, BT, &Asm[0][0], &Bsm[0][0], m0, n0, w, l, acc);
  const int lr = l & 15, lg = l >> 4;
#pragma unroll
  for (int mi = 0; mi < 4; ++mi)
#pragma unroll
    for (int ni = 0; ni < 4; ++ni)
#pragma unroll
      for (int r = 0; r < 4; ++r) {
        int row = m0 + (w >> 1) * 64 + mi * 16 + lg * 4 + r;
        int col = n0 + (w & 1) * 64 + ni * 16 + lr;
        float v = acc[mi][ni][r] + bias[col];
        int hh = col >> 7, hd = col & 127;
        if (z == 0) {
          Qs[(size_t)hh * QLEN * HD + (size_t)row * HD + hd] = (__bf16)(v * 0.08838834764831845f);
        } else if (z == 1) {
          Kall[(size_t)hh * KVLEN * HD + (size_t)(PLEN + row) * HD + hd] = (__bf16)v;
        } else {
          VT[(size_t)hh * HD * KVLEN + (size_t)hd * KVLEN + (PLEN + row)] = (__bf16)v;
        }
      }
}

// final: out[q][d] = O[q][:] . WoT[d][:] + bout[d]  (f32 out).  128x64 tiles, 512 blocks.
// r12-proven BK=64 (MFMA/barrier genuinely doubled since BN stays 64).
__global__ __launch_bounds__(256) void gemm_out(const __bf16* __restrict__ Ob,
                                                const __bf16* __restrict__ WoT,
                                                const float* __restrict__ bout,
                                                float* __restrict__ out) {
  __shared__ __bf16 Asm[2][2][4096];   // [dbuf][sub][128x32]
  __shared__ __bf16 Bsm[2][2][2048];   // [dbuf][sub][64x32]
  const int t = threadIdx.x, w = t >> 6, l = t & 63;
  const int m0 = blockIdx.x * 128, n0 = blockIdx.y * 64;
  const int lr = l & 15, lg = l >> 4;
  f32x4 acc[4][2];
#pragma unroll
  for (int mi = 0; mi < 4; ++mi)
#pragma unroll
    for (int ni = 0; ni < 2; ++ni) acc[mi][ni] = (f32x4){0.f, 0.f, 0.f, 0.f};

  stage_tile<64>(Ob, WoT, (char*)&Asm[0][0][0], (char*)&Bsm[0][0][0], m0, n0, 0, w, l);
  stage_tile<64>(Ob, WoT, (char*)&Asm[0][1][0], (char*)&Bsm[0][1][0], m0, n0, 32, w, l);
  __syncthreads();
  int cur = 0;
  for (int k0 = 0; k0 < DMODEL; k0 += 64) {
    if (k0 + 64 < DMODEL) {
      stage_tile<64>(Ob, WoT, (char*)&Asm[cur ^ 1][0][0], (char*)&Bsm[cur ^ 1][0][0],
                     m0, n0, k0 + 64, w, l);
      stage_tile<64>(Ob, WoT, (char*)&Asm[cur ^ 1][1][0], (char*)&Bsm[cur ^ 1][1][0],
                     m0, n0, k0 + 96, w, l);
    }
#pragma unroll
    for (int sub = 0; sub < 2; ++sub) {
      const __bf16* Ab = &Asm[cur][sub][0];
      const __bf16* Bb = &Bsm[cur][sub][0];
      bf16x8 af[4], bfv[2];
#pragma unroll
      for (int mi = 0; mi < 4; ++mi)
        af[mi] = *(const bf16x8*)(Ab + ((w >> 1) * 64 + mi * 16 + lr) * 32 + lg * 8);
#pragma unroll
      for (int ni = 0; ni < 2; ++ni)
        bfv[ni] = *(const bf16x8*)(Bb + ((w & 1) * 32 + ni * 16 + lr) * 32 + lg * 8);
      __builtin_amdgcn_s_setprio(1);
#pragma unroll
      for (int mi = 0; mi < 4; ++mi)
#pragma unroll
        for (int ni = 0; ni < 2; ++ni)
          acc[mi][ni] = __builtin_amdgcn_mfma_f32_16x16x32_bf16(af[mi], bfv[ni], acc[mi][ni], 0, 0, 0);
      __builtin_amdgcn_s_setprio(0);
    }
    __syncthreads();
    cur ^= 1;
  }
#pragma unroll
  for (int mi = 0; mi < 4; ++mi)
#pragma unroll
    for (int ni = 0; ni < 2; ++ni)
#pragma unroll
      for (int r = 0; r < 4; ++r) {
        int row = m0 + (w >> 1) * 64 + mi * 16 + lg * 4 + r;
        int col = n0 + (w & 1) * 32 + ni * 16 + lr;
        out[(size_t)row * DMODEL + col] = acc[mi][ni][r] + bout[col];
      }
}

// ---------------- attention (r8/r11/r12 exact: balanced K-split + swapped-QK in-register P) ----------------
template <int KS>
__global__ __launch_bounds__(256, 4) void k_attn(const __bf16* __restrict__ Qs,
                                                 const __bf16* __restrict__ Kall,
                                                 const __bf16* __restrict__ VT,
                                                 __bf16* __restrict__ P1buf,
                                                 float* __restrict__ S1buf,
                                                 __bf16* __restrict__ P2buf,
                                                 float* __restrict__ S2buf) {
  __shared__ __bf16 Ksm[2][4096];   // [buf][32 kv][128 hd] (xor-swizzled)
  __shared__ __bf16 Vsm[2][4096];   // [buf][128 hd][32 kv] (xor-swizzled)
  const int id = blockIdx.x;
  const int b = id & 255, k = id >> 8;
  const int h = b >> 4, m = b & 15;
  int qt, z;
  if constexpr (KS == 2) {
    z = k >> 1;
    const int j = 2 * m + (k >> 1);
    qt = (k & 1) ? (31 - j) : j;
  } else {
    z = 0;
    qt = (k & 1) ? (31 - 2 * m) : (2 * m);
  }
  const int t = threadIdx.x, w = t >> 6, l = t & 63;
  const int lr = l & 15, lg = l >> 4;
  const int q0 = qt * 64 + w * 16;
  const __bf16* Qh = Qs + (size_t)h * QLEN * HD;
  const char* Khb = (const char*)(Kall + (size_t)h * KVLEN * HD);
  const char* Vhb = (const char*)(VT + (size_t)h * HD * KVLEN);

  bf16x8 qf[4];
#pragma unroll
  for (int c = 0; c < 4; ++c)
    qf[c] = *(const bf16x8*)(Qh + (size_t)(q0 + lr) * HD + c * 32 + lg * 8);

  f32x4 acc[8];
  float ss;

  auto STAGE = [&](int buf, int kb) {
#pragma unroll
    for (int i = 0; i < 2; ++i) {  // K: 8KB, rows contiguous in global
      int o = (i * 256 + w * 64 + l) * 16;
      int po = o ^ (((o >> 8) & 7) << 4);
      gload_lds16(Khb + (size_t)kb * 256 + po, (char*)&Ksm[buf][0] + i * 4096 + w * 1024);
    }
#pragma unroll
    for (int i = 0; i < 2; ++i) {  // V: 8KB, rows strided KVLEN*2 in global VT
      int o = (i * 256 + w * 64 + l) * 16;
      int po = o ^ (((o >> 7) & 7) << 4);
      int row = po >> 6, colb = po & 63;
      gload_lds16(Vhb + (size_t)row * (KVLEN * 2) + (size_t)kb * 2 + colb,
                  (char*)&Vsm[buf][0] + i * 4096 + w * 1024);
    }
  };

  auto COMPUTE = [&](int buf, int mrel, bool domask) {
    const char* Kb = (const char*)&Ksm[buf][0];
    const char* Vb = (const char*)&Vsm[buf][0];
    f32x4 st0 = {0.f, 0.f, 0.f, 0.f}, st1 = {0.f, 0.f, 0.f, 0.f};
    __builtin_amdgcn_s_setprio(1);
#pragma unroll
    for (int c = 0; c < 4; ++c) {
      int o0 = lr * 256 + c * 64 + lg * 16;        o0 ^= ((o0 >> 8) & 7) << 4;
      int o1 = (16 + lr) * 256 + c * 64 + lg * 16; o1 ^= ((o1 >> 8) & 7) << 4;
      bf16x8 kf0 = *(const bf16x8*)(Kb + o0);
      bf16x8 kf1 = *(const bf16x8*)(Kb + o1);
      st0 = __builtin_amdgcn_mfma_f32_16x16x32_bf16(kf0, qf[c], st0, 0, 0, 0);
      st1 = __builtin_amdgcn_mfma_f32_16x16x32_bf16(kf1, qf[c], st1, 0, 0, 0);
    }
    __builtin_amdgcn_s_setprio(0);
    const int qabs = q0 + lr;
    float e0[4], e1[4];
    float ps = 0.f;
#pragma unroll
    for (int r = 0; r < 4; ++r) {
      e0[r] = __expf(st0[r] - 16.0f);
      e1[r] = __expf(st1[r] - 16.0f);
      if (domask) {
        if (mrel + 4 * lg + r > qabs) e0[r] = 0.f;
        if (mrel + 16 + 4 * lg + r > qabs) e1[r] = 0.f;
      }
      ps += e0[r] + e1[r];
    }
    ss += ps;
    unsigned W0 = cvt_pk_bf16(e0[0], e0[1]);
    unsigned W1 = cvt_pk_bf16(e0[2], e0[3]);
    unsigned W2 = cvt_pk_bf16(e1[0], e1[1]);
    unsigned W3 = cvt_pk_bf16(e1[2], e1[3]);
    const int srcA = lr + (((2 * lg) & 3) << 4);
    const int srcB = lr + (((2 * lg + 1) & 3) << 4);
    unsigned A0 = __shfl(W0, srcA), A1 = __shfl(W1, srcA);
    unsigned A2 = __shfl(W0, srcB), A3 = __shfl(W1, srcB);
    unsigned B0 = __shfl(W2, srcA), B1 = __shfl(W3, srcA);
    unsigned B2 = __shfl(W2, srcB), B3 = __shfl(W3, srcB);
    union { unsigned u[4]; bf16x8 v; } pu;
    pu.u[0] = (lg < 2) ? A0 : B0;
    pu.u[1] = (lg < 2) ? A1 : B1;
    pu.u[2] = (lg < 2) ? A2 : B2;
    pu.u[3] = (lg < 2) ? A3 : B3;
    bf16x8 pf = pu.v;
    __builtin_amdgcn_s_setprio(1);
#pragma unroll
    for (int c = 0; c < 8; ++c) {
      int o = (c * 16 + lr) * 64 + lg * 16; o ^= ((o >> 7) & 7) << 4;
      bf16x8 vf = *(const bf16x8*)(Vb + o);
      acc[c] = __builtin_amdgcn_mfma_f32_16x16x32_bf16(pf, vf, acc[c], 0, 0, 0);
    }
    __builtin_amdgcn_s_setprio(0);
  };

  auto STORE_PHASE = [&](__bf16* PBUF, float* SBUF) {
    const size_t rb = (size_t)(z * NH + h) * QLEN;
    float s = ss;
    s += __shfl_xor(s, 16);
    s += __shfl_xor(s, 32);
    if (l < 16) SBUF[rb + q0 + l] = s;
#pragma unroll
    for (int r = 0; r < 4; ++r) {
      const int row = q0 + lg * 4 + r;
#pragma unroll
      for (int c = 0; c < 8; ++c)
        PBUF[(rb + row) * HD + c * 16 + lr] = (__bf16)acc[c][r];
    }
  };

#pragma unroll
  for (int c = 0; c < 8; ++c) acc[c] = (f32x4){0.f, 0.f, 0.f, 0.f};
  ss = 0.f;
  int cur = 0;
  STAGE(0, z * 32);
  __syncthreads();
#pragma unroll 1
  for (int tt = z; tt < 16; tt += KS) {
    if (tt + KS < 16) STAGE(cur ^ 1, (tt + KS) * 32);
    else STAGE(cur ^ 1, PLEN + z * 32);
    COMPUTE(cur, 0, false);
    __syncthreads();
    cur ^= 1;
  }
  STORE_PHASE(P1buf, S1buf);

#pragma unroll
  for (int c = 0; c < 8; ++c) acc[c] = (f32x4){0.f, 0.f, 0.f, 0.f};
  ss = 0.f;
  const int ntb = 2 * qt + 2;
#pragma unroll 1
  for (int tt = z; tt < ntb; tt += KS) {
    if (tt + KS < ntb) STAGE(cur ^ 1, PLEN + (tt + KS) * 32);
    COMPUTE(cur, tt * 32, tt * 32 + 31 > q0);
    __syncthreads();
    cur ^= 1;
  }
  STORE_PHASE(P2buf, S2buf);
}

// combine K-split partials: Ob = g*ΣP1/Σs1 + ΣP2/Σs2  (vectorized x8, r12 exact)
template <int KS>
__global__ __launch_bounds__(256) void k_combine(const __bf16* __restrict__ P1buf,
                                                 const float* __restrict__ S1buf,
                                                 const __bf16* __restrict__ P2buf,
                                                 const float* __restrict__ S2buf,
                                                 const float* __restrict__ gate,
                                                 __bf16* __restrict__ Ob) {
  const int idx = blockIdx.x * 256 + threadIdx.x;  // 8 elems each
  const int dc = (idx & 15) * 8;
  const int q = (idx >> 4) & 2047;
  const int h = idx >> 15;
  const size_t rq = (size_t)h * QLEN + q;
  float a1[8], a2[8];
#pragma unroll
  for (int j = 0; j < 8; ++j) { a1[j] = 0.f; a2[j] = 0.f; }
  float s1 = 0.f, s2 = 0.f;
#pragma unroll
  for (int zz = 0; zz < KS; ++zz) {
    const size_t zb = (size_t)zz * NH * QLEN;
    bf16x8 p1 = *(const bf16x8*)&P1buf[(zb + rq) * HD + dc];
    bf16x8 p2 = *(const bf16x8*)&P2buf[(zb + rq) * HD + dc];
#pragma unroll
    for (int j = 0; j < 8; ++j) {
      a1[j] += (float)p1[j];
      a2[j] += (float)p2[j];
    }
    s1 += S1buf[zb + rq];
    s2 += S2buf[zb + rq];
  }
  const float f1 = gate[h] / s1;
  const float f2 = 1.0f / s2;
  bf16x8 ov;
#pragma unroll
  for (int j = 0; j < 8; ++j) ov[j] = (__bf16)(a1[j] * f1 + a2[j] * f2);
  *(bf16x8*)&Ob[(size_t)q * DMODEL + h * HD + dc] = ov;
}

// ---------------- launch ----------------

extern "C" void kernel_launch(void* const* d_in, const int* in_sizes, int n_in,
                              void* d_out, int out_size, void* d_ws, size_t ws_size,
                              hipStream_t stream) {
  const float* x    = (const float*)d_in[0];
  const float* pk   = (const float*)d_in[1];
  const float* pv   = (const float*)d_in[2];
  const float* Wq   = (const float*)d_in[3];
  const float* bq   = (const float*)d_in[4];
  const float* Wk   = (const float*)d_in[5];
  const float* bk   = (const float*)d_in[6];
  const float* Wv   = (const float*)d_in[7];
  const float* bv   = (const float*)d_in[8];
  const float* gate = (const float*)d_in[9];
  const float* Wout = (const float*)d_in[10];
  const float* bout = (const float*)d_in[11];
  float* out = (float*)d_out;

  char* ws = (char*)d_ws;
  size_t off = 0;
  auto alc = [&](size_t bytes) -> char* {
    char* p = ws + off;
    off += bytes;
    off = (off + 255) & ~(size_t)255;
    return p;
  };
  __bf16* xb   = (__bf16*)alc((size_t)DMODEL * DMODEL * 2);
  __bf16* WqT  = (__bf16*)alc((size_t)DMODEL * DMODEL * 2);
  __bf16* WkT  = (__bf16*)alc((size_t)DMODEL * DMODEL * 2);
  __bf16* WvT  = (__bf16*)alc((size_t)DMODEL * DMODEL * 2);
  __bf16* WoT  = (__bf16*)alc((size_t)DMODEL * DMODEL * 2);
  __bf16* Qs   = (__bf16*)alc((size_t)NH * QLEN * HD * 2);
  __bf16* Kall = (__bf16*)alc((size_t)NH * KVLEN * HD * 2);
  __bf16* VTa  = (__bf16*)alc((size_t)NH * HD * KVLEN * 2);
  __bf16* Ob   = (__bf16*)alc((size_t)QLEN * DMODEL * 2);

  const size_t per_split = (size_t)NH * QLEN * HD * 2 * 2
                         + (size_t)NH * QLEN * 4 * 2 + 1024;
  int KS = (off + 2 * per_split <= ws_size) ? 2 : 1;
  __bf16* P1buf = (__bf16*)alc((size_t)KS * NH * QLEN * HD * 2);
  __bf16* P2buf = (__bf16*)alc((size_t)KS * NH * QLEN * HD * 2);
  float*  S1buf = (float*)alc((size_t)KS * NH * QLEN * 4);
  float*  S2buf = (float*)alc((size_t)KS * NH * QLEN * 4);

  k_prep<<<dim3(32, 32, 7), 256, 0, stream>>>(Wq, Wk, Wv, Wout, x, pk, pv,
                                              WqT, WkT, WvT, WoT, xb, Kall, VTa);

  gemm_qkv<<<dim3(16, 16, 3), 256, 0, stream>>>(xb, WqT, WkT, WvT, bq, bk, bv, Qs, Kall, VTa);

  const int ncomb = (NH * QLEN * HD / 8) / 256;  // 2048 blocks, 8 elems/thread
  if (KS == 2) {
    k_attn<2><<<1024, 256, 0, stream>>>(Qs, Kall, VTa, P1buf, S1buf, P2buf, S2buf);
    k_combine<2><<<ncomb, 256, 0, stream>>>(P1buf, S1buf, P2buf, S2buf, gate, Ob);
  } else {
    k_attn<1><<<512, 256, 0, stream>>>(Qs, Kall, VTa, P1buf, S1buf, P2buf, S2buf);
    k_combine<1><<<ncomb, 256, 0, stream>>>(P1buf, S1buf, P2buf, S2buf, gate, Ob);
  }
  gemm_out<<<dim3(16, 32), 256, 0, stream>>>(Ob, WoT, bout, out);
}